// Round 1
// baseline (606.244 us; speedup 1.0000x reference)
//
#include <hip/hip_runtime.h>
#include <hip/hip_bf16.h>

#define N_NODES 50000
#define N_EDGES 800000
#define F_IN 128
#define HEADS 8
#define HID 16
#define HC 128  // HEADS*HID

// ---------------------------------------------------------------------------
// K1: fused dual GEMM  xl = x@Wl + bl, xr = x@Wr + br   (fp32)
// block = 256 threads: threads 0-127 -> Wl cols, 128-255 -> Wr cols.
// Each block handles 16 rows of x staged in LDS; per-thread 16-row accumulator.
// ---------------------------------------------------------------------------
__global__ __launch_bounds__(256) void k_gemm(
    const float* __restrict__ x,
    const float* __restrict__ Wl, const float* __restrict__ bl,
    const float* __restrict__ Wr, const float* __restrict__ br,
    float* __restrict__ xl, float* __restrict__ xr) {
  __shared__ float xs[16 * 128];
  const int t = threadIdx.x;
  const int block_row = blockIdx.x * 16;

  // stage 16x128 fp32 tile (512 float4, 2 per thread)
  const float4* xsrc = (const float4*)(x + (size_t)block_row * F_IN);
  float4* xd = (float4*)xs;
  xd[t] = xsrc[t];
  xd[t + 256] = xsrc[t + 256];
  __syncthreads();

  const int col = t & 127;
  const bool right = t >= 128;
  const float* __restrict__ W = right ? Wr : Wl;
  const float* __restrict__ bv = right ? br : bl;

  float acc[16];
#pragma unroll
  for (int r = 0; r < 16; ++r) acc[r] = 0.f;

  for (int k = 0; k < 128; k += 4) {
    const float w0 = W[(k + 0) * HC + col];
    const float w1 = W[(k + 1) * HC + col];
    const float w2 = W[(k + 2) * HC + col];
    const float w3 = W[(k + 3) * HC + col];
#pragma unroll
    for (int r = 0; r < 16; ++r) {
      const float4 xv = *((const float4*)(xs + r * 128 + k));  // wave-uniform: LDS broadcast
      acc[r] = fmaf(xv.x, w0, acc[r]);
      acc[r] = fmaf(xv.y, w1, acc[r]);
      acc[r] = fmaf(xv.z, w2, acc[r]);
      acc[r] = fmaf(xv.w, w3, acc[r]);
    }
  }
  const float b = bv[col];
  float* __restrict__ dst = right ? xr : xl;
#pragma unroll
  for (int r = 0; r < 16; ++r)
    dst[(size_t)(block_row + r) * HC + col] = acc[r] + b;
}

// ---------------------------------------------------------------------------
// K2: per-(edge,head) attention logit -> ex = exp(logit); denom[dst][h] += ex
// ---------------------------------------------------------------------------
__global__ __launch_bounds__(256) void k_edge(
    const int* __restrict__ eidx, const float* __restrict__ eattr,
    const float* __restrict__ We, const float* __restrict__ be,
    const float* __restrict__ att,
    const float* __restrict__ xl, const float* __restrict__ xr,
    float* __restrict__ ex, float* __restrict__ denom) {
  const int tid = blockIdx.x * 256 + threadIdx.x;
  if (tid >= N_EDGES * HEADS) return;
  const int e = tid >> 3;
  const int h = tid & 7;
  const int src = eidx[e];
  const int dst = eidx[N_EDGES + e];
  const float2 ea = *(const float2*)(eattr + (size_t)e * 2);

  const float4* xl4 = (const float4*)(xl + (size_t)src * HC + h * HID);
  const float4* xr4 = (const float4*)(xr + (size_t)dst * HC + h * HID);
  const float4* w04 = (const float4*)(We + h * HID);
  const float4* w14 = (const float4*)(We + HC + h * HID);
  const float4* be4 = (const float4*)(be + h * HID);
  const float4* at4 = (const float4*)(att + h * HID);

  float logit = 0.f;
#pragma unroll
  for (int j = 0; j < 4; ++j) {
    const float4 a = xl4[j], b = xr4[j];
    const float4 w0 = w04[j], w1 = w14[j], bb = be4[j], av = at4[j];
    float m0 = a.x + b.x + fmaf(ea.x, w0.x, fmaf(ea.y, w1.x, bb.x));
    float m1 = a.y + b.y + fmaf(ea.x, w0.y, fmaf(ea.y, w1.y, bb.y));
    float m2 = a.z + b.z + fmaf(ea.x, w0.z, fmaf(ea.y, w1.z, bb.z));
    float m3 = a.w + b.w + fmaf(ea.x, w0.w, fmaf(ea.y, w1.w, bb.w));
    m0 = m0 > 0.f ? m0 : 0.2f * m0;
    m1 = m1 > 0.f ? m1 : 0.2f * m1;
    m2 = m2 > 0.f ? m2 : 0.2f * m2;
    m3 = m3 > 0.f ? m3 : 0.2f * m3;
    logit = fmaf(m0, av.x, logit);
    logit = fmaf(m1, av.y, logit);
    logit = fmaf(m2, av.z, logit);
    logit = fmaf(m3, av.w, logit);
  }
  const float exv = expf(logit);
  ex[tid] = exv;
  atomicAdd(&denom[(size_t)dst * HEADS + h], exv);
}

// ---------------------------------------------------------------------------
// K3a: degree histogram over dst
// ---------------------------------------------------------------------------
__global__ __launch_bounds__(256) void k_deg(const int* __restrict__ eidx,
                                             int* __restrict__ deg) {
  const int e = blockIdx.x * 256 + threadIdx.x;
  if (e < N_EDGES) atomicAdd(&deg[eidx[N_EDGES + e]], 1);
}

// ---------------------------------------------------------------------------
// K3b: single-block exclusive scan of degrees -> offs[0..N_NODES]
// ---------------------------------------------------------------------------
__global__ __launch_bounds__(1024) void k_scan(const int* __restrict__ deg,
                                               int* __restrict__ offs) {
  __shared__ int sm[1024];
  __shared__ int running;
  const int t = threadIdx.x;
  if (t == 0) running = 0;
  __syncthreads();
  for (int base = 0; base < N_NODES; base += 4096) {
    const int i0 = base + t * 4;
    int v0 = 0, v1 = 0, v2 = 0, v3 = 0;
    if (i0 + 3 < N_NODES) {
      const int4 q = *(const int4*)(deg + i0);
      v0 = q.x; v1 = q.y; v2 = q.z; v3 = q.w;
    } else {
      if (i0 + 0 < N_NODES) v0 = deg[i0 + 0];
      if (i0 + 1 < N_NODES) v1 = deg[i0 + 1];
      if (i0 + 2 < N_NODES) v2 = deg[i0 + 2];
      if (i0 + 3 < N_NODES) v3 = deg[i0 + 3];
    }
    const int s = v0 + v1 + v2 + v3;
    sm[t] = s;
    __syncthreads();
    for (int off = 1; off < 1024; off <<= 1) {
      const int add = (t >= off) ? sm[t - off] : 0;
      __syncthreads();
      sm[t] += add;
      __syncthreads();
    }
    const int excl = sm[t] - s + running;
    const int total = sm[1023];
    if (i0 + 0 < N_NODES) offs[i0 + 0] = excl;
    if (i0 + 1 < N_NODES) offs[i0 + 1] = excl + v0;
    if (i0 + 2 < N_NODES) offs[i0 + 2] = excl + v0 + v1;
    if (i0 + 3 < N_NODES) offs[i0 + 3] = excl + v0 + v1 + v2;
    __syncthreads();
    if (t == 0) running += total;
    __syncthreads();
  }
  if (t == 0) offs[N_NODES] = running;
}

// ---------------------------------------------------------------------------
// K3c: scatter edge ids into CSR
// ---------------------------------------------------------------------------
__global__ __launch_bounds__(256) void k_scatter(
    const int* __restrict__ eidx, const int* __restrict__ offs,
    int* __restrict__ cursor, int* __restrict__ eids) {
  const int e = blockIdx.x * 256 + threadIdx.x;
  if (e < N_EDGES) {
    const int d = eidx[N_EDGES + e];
    const int pos = atomicAdd(&cursor[d], 1);
    eids[offs[d] + pos] = e;
  }
}

// ---------------------------------------------------------------------------
// K4: per-node aggregation. One 64-lane wave per node; lane owns 2 channels.
// out[node][c] = sum_e alpha[e][h(c)] * xl[src(e)][c]     (pre-BN, bias skipped)
// ---------------------------------------------------------------------------
__global__ __launch_bounds__(256) void k_agg(
    const int* __restrict__ eidx, const int* __restrict__ offs,
    const int* __restrict__ eids, const float* __restrict__ ex,
    const float* __restrict__ denom, const float* __restrict__ xl,
    float* __restrict__ outp) {
  const int wave = threadIdx.x >> 6;
  const int lane = threadIdx.x & 63;
  const int node = blockIdx.x * 4 + wave;
  if (node >= N_NODES) return;
  const int h = lane >> 3;  // (lane*2)/16
  const float dn = denom[(size_t)node * HEADS + h];
  const float inv = dn > 0.f ? 1.0f / dn : 0.f;
  const int beg = offs[node], end = offs[node + 1];
  float a0 = 0.f, a1 = 0.f;
  for (int k = beg; k < end; ++k) {
    const int e = eids[k];
    const float alpha = ex[(size_t)e * HEADS + h] * inv;
    const int src = eidx[e];
    const float2 v = *((const float2*)(xl + (size_t)src * HC) + lane);
    a0 = fmaf(alpha, v.x, a0);
    a1 = fmaf(alpha, v.y, a1);
  }
  float2 o; o.x = a0; o.y = a1;
  *((float2*)(outp + (size_t)node * HC) + lane) = o;
}

// ---------------------------------------------------------------------------
// K5: per-channel sum / sumsq over nodes (for BatchNorm batch stats)
// ---------------------------------------------------------------------------
__global__ __launch_bounds__(256) void k_stats(const float* __restrict__ outp,
                                               float* __restrict__ stats) {
  const int c = threadIdx.x & 127;
  const int half = threadIdx.x >> 7;
  float s1 = 0.f, s2 = 0.f;
  for (int r = blockIdx.x * 2 + half; r < N_NODES; r += gridDim.x * 2) {
    const float v = outp[(size_t)r * HC + c];
    s1 += v;
    s2 = fmaf(v, v, s2);
  }
  __shared__ float sm[512];
  sm[threadIdx.x] = s1;
  sm[256 + threadIdx.x] = s2;
  __syncthreads();
  if (threadIdx.x < 128) {
    s1 = sm[threadIdx.x] + sm[threadIdx.x + 128];
    s2 = sm[256 + threadIdx.x] + sm[256 + threadIdx.x + 128];
    atomicAdd(&stats[c], s1);
    atomicAdd(&stats[128 + c], s2);
  }
}

// ---------------------------------------------------------------------------
// K6: BatchNorm (batch stats) + LeakyReLU(0.01), in place on outp
// ---------------------------------------------------------------------------
__global__ __launch_bounds__(256) void k_bn(const float* __restrict__ stats,
                                            const float* __restrict__ gamma,
                                            const float* __restrict__ beta,
                                            float* __restrict__ outp) {
  const int i = blockIdx.x * 256 + threadIdx.x;
  if (i >= N_NODES * HC) return;
  const int c = i & 127;
  const float mean = stats[c] * (1.0f / N_NODES);
  const float var = stats[128 + c] * (1.0f / N_NODES) - mean * mean;
  const float rstd = rsqrtf(var + 1e-5f);
  float v = (outp[i] - mean) * rstd * gamma[c] + beta[c];
  outp[i] = v > 0.f ? v : 0.01f * v;
}

// ---------------------------------------------------------------------------
extern "C" void kernel_launch(void* const* d_in, const int* in_sizes, int n_in,
                              void* d_out, int out_size, void* d_ws, size_t ws_size,
                              hipStream_t stream) {
  const float* x     = (const float*)d_in[0];
  const int*   eidx  = (const int*)d_in[1];
  const float* eattr = (const float*)d_in[2];
  const float* Wl    = (const float*)d_in[3];
  const float* bl    = (const float*)d_in[4];
  const float* Wr    = (const float*)d_in[5];
  const float* br    = (const float*)d_in[6];
  const float* We    = (const float*)d_in[7];
  const float* be    = (const float*)d_in[8];
  const float* att   = (const float*)d_in[9];
  // d_in[10] = bias: cancels exactly in BatchNorm (mean subtraction) -> unused
  const float* gamma = (const float*)d_in[11];
  const float* beta  = (const float*)d_in[12];
  float* out = (float*)d_out;

  char* ws = (char*)d_ws;
  size_t off = 0;
  auto alloc = [&](size_t bytes) {
    size_t o = off;
    off = (off + bytes + 15) & ~size_t(15);
    return o;
  };
  const size_t o_denom = alloc((size_t)N_NODES * HEADS * 4);
  const size_t o_deg   = alloc((size_t)(N_NODES + 1) * 4);
  const size_t o_cur   = alloc((size_t)N_NODES * 4);
  const size_t o_stats = alloc(256 * 4);
  const size_t zero_bytes = off;  // everything above must start zeroed
  const size_t o_xl   = alloc((size_t)N_NODES * HC * 4);
  const size_t o_xr   = alloc((size_t)N_NODES * HC * 4);
  const size_t o_ex   = alloc((size_t)N_EDGES * HEADS * 4);
  const size_t o_offs = alloc((size_t)(N_NODES + 1) * 4);
  const size_t o_eid  = alloc((size_t)N_EDGES * 4);
  (void)ws_size; (void)in_sizes; (void)n_in; (void)out_size; (void)o_eid;

  float* denom = (float*)(ws + o_denom);
  int*   deg   = (int*)(ws + o_deg);
  int*   cur   = (int*)(ws + o_cur);
  float* stats = (float*)(ws + o_stats);
  float* xl    = (float*)(ws + o_xl);
  float* xr    = (float*)(ws + o_xr);
  float* ex    = (float*)(ws + o_ex);
  int*   offs  = (int*)(ws + o_offs);
  int*   eids  = (int*)(ws + o_eid);

  hipMemsetAsync(ws, 0, zero_bytes, stream);

  k_gemm<<<N_NODES / 16, 256, 0, stream>>>(x, Wl, bl, Wr, br, xl, xr);
  k_deg<<<(N_EDGES + 255) / 256, 256, 0, stream>>>(eidx, deg);
  k_scan<<<1, 1024, 0, stream>>>(deg, offs);
  k_scatter<<<(N_EDGES + 255) / 256, 256, 0, stream>>>(eidx, offs, cur, eids);
  k_edge<<<(N_EDGES * HEADS + 255) / 256, 256, 0, stream>>>(eidx, eattr, We, be,
                                                            att, xl, xr, ex, denom);
  k_agg<<<N_NODES / 4, 256, 0, stream>>>(eidx, offs, eids, ex, denom, xl, out);
  k_stats<<<256, 256, 0, stream>>>(out, stats);
  k_bn<<<(N_NODES * HC + 255) / 256, 256, 0, stream>>>(stats, gamma, beta, out);
}